// Round 2
// 5196.890 us; speedup vs baseline: 1.2024x; 1.2024x over previous
//
#include <hip/hip_runtime.h>
#include <stdint.h>

#define B_   128
#define S_   256
#define I_   256
#define H_   1024
#define O_   256
#define BSO  (B_*S_*O_)

typedef unsigned short u16;
typedef unsigned int   u32;
typedef unsigned long long u64;

using short8 = __attribute__((ext_vector_type(8))) short;   // 8 bf16 in 4 VGPRs
using float8 = __attribute__((ext_vector_type(8))) float;   // 8 fp32 in 8 VGPRs
using f32x4  = __attribute__((ext_vector_type(4))) float;

__device__ __forceinline__ float bf2f(u16 u) {
    return __uint_as_float(((u32)u) << 16);
}
__device__ __forceinline__ u16 f2bf(float f) {
    u32 x = __float_as_uint(f);
    x += 0x7FFFu + ((x >> 16) & 1u);   // RNE
    return (u16)(x >> 16);
}
__device__ __forceinline__ float clampf_(float x, float lo, float hi) {
    x = (x < hi) ? x : hi;
    x = (x > lo) ? x : lo;
    return x;
}
__device__ __forceinline__ float sigmoidf_(float x) {
    x = clampf_(x, -60.f, 60.f);
    return 1.0f / (1.0f + __expf(-x));
}
__device__ __forceinline__ float tanhf_(float x) {
    float x2 = clampf_(2.0f * x, -30.0f, 30.0f);
    float e = __expf(x2);
    return (e - 1.0f) / (e + 1.0f);
}

__device__ __forceinline__ float loadf(const float* p) { return *p; }
__device__ __forceinline__ float loadf(const u16* p)   { return bf2f(*p); }

template<typename T> struct V8S;
template<> struct V8S<u16>   { using t = short8; };
template<> struct V8S<float> { using t = float8; };

__device__ __forceinline__ short8 to_bf8(short8 v) { return v; }
__device__ __forceinline__ short8 to_bf8(float8 v) {
    short8 r;
    #pragma unroll
    for (int j = 0; j < 8; j++) r[j] = (short)f2bf(v[j]);
    return r;
}

// ---------------------------------------------------------------------------
// init: pack h0 (B,L,H) fp32 into per-layer exchange buffers (u32 = 2 bf16).
// ex layout per layer: [group g][batch-in-group bl][512 u32 (1024 cols)]
__global__ void init_h(const float* __restrict__ h0, u32* __restrict__ ex0, u32* __restrict__ ex1)
{
    int idx = blockIdx.x * 256 + threadIdx.x;   // over 128*512
    int bg = idx >> 9;          // global batch
    int cp = idx & 511;         // u32 column pair
    int g  = bg >> 4, bl = bg & 15;
    u32 lo0 = f2bf(h0[bg * 2048 + 2 * cp]);
    u32 hi0 = f2bf(h0[bg * 2048 + 2 * cp + 1]);
    ex0[g * 8192 + bl * 512 + cp] = lo0 | (hi0 << 16);
    u32 lo1 = f2bf(h0[bg * 2048 + 1024 + 2 * cp]);
    u32 hi1 = f2bf(h0[bg * 2048 + 1024 + 2 * cp + 1]);
    ex1[g * 8192 + bl * 512 + cp] = lo1 | (hi1 << 16);
}

// fp32 -> bf16 bulk convert
__global__ void cvt_bf(const float* __restrict__ in, u16* __restrict__ out, int n)
{
    int i = blockIdx.x * 256 + threadIdx.x;
    if (i < n) out[i] = f2bf(in[i]);
}

// ---------------------------------------------------------------------------
// scalar-gate projections: xz[m] = X[m,:]·Wz ; xr[m] = X[m,:]·Wr + br
template<typename XT>
__global__ __launch_bounds__(256, 4)
void proj_zr(const XT* __restrict__ X, const float* __restrict__ Wz,
             const float* __restrict__ Wr, const float* __restrict__ br,
             float* __restrict__ xz, float* __restrict__ xr, int K)
{
    const int lane = threadIdx.x & 63;
    const int wv   = threadIdx.x >> 6;
    const long m   = (long)blockIdx.x * 4 + wv;
    const XT* xp   = X + m * K;
    float az = 0.f, ar = 0.f;
    for (int i = lane; i < K; i += 64) {
        float xv = loadf(xp + i);
        az = fmaf(xv, Wz[i], az);
        ar = fmaf(xv, Wr[i], ar);
    }
    #pragma unroll
    for (int o = 1; o < 64; o <<= 1) { az += __shfl_xor(az, o); ar += __shfl_xor(ar, o); }
    if (lane == 0) {
        xz[m] = clampf_(az, -1e4f, 1e4f);
        xr[m] = clampf_(ar + br[0], -1e4f, 1e4f);
    }
}

// ---------------------------------------------------------------------------
// C[M,N] = A[M,K] · W[N,K]^T.  A: fp32 or bf16; W fp32 (both -> bf16 at LDS).
// MODE 0: store bf16. MODE 1: store fp32 sigmoid(val + bias[n]).
template<int MODE, typename AT>
__global__ __launch_bounds__(256, 2)
void gemm_bt(const AT* __restrict__ A, const float* __restrict__ W,
             const float* __restrict__ bias, void* __restrict__ Cv,
             int M, int N, int K)
{
    __shared__ alignas(16) u16 As[128 * 32];
    __shared__ alignas(16) u16 Ws[128 * 32];
    const int tid  = threadIdx.x;
    const int lane = tid & 63;
    const int wv   = tid >> 6;
    const int l15  = lane & 15;
    const int quad = lane >> 4;
    const int wm   = wv >> 1, wn = wv & 1;
    const long m0  = (long)blockIdx.y * 128;
    const long n0  = (long)blockIdx.x * 128;

    const int c0 = tid, c1 = tid + 256;
    const long ar0 = (m0 + (c0 >> 2)) * (long)K + (c0 & 3) * 8;
    const long ar1 = (m0 + (c1 >> 2)) * (long)K + (c1 & 3) * 8;
    const long wr0 = (n0 + (c0 >> 2)) * (long)K + (c0 & 3) * 8;
    const long wr1 = (n0 + (c1 >> 2)) * (long)K + (c1 & 3) * 8;

    f32x4 zero4 = {0.f, 0.f, 0.f, 0.f};
    f32x4 acc[4][4];
    #pragma unroll
    for (int i = 0; i < 4; i++)
        #pragma unroll
        for (int j = 0; j < 4; j++) acc[i][j] = zero4;

    typename V8S<AT>::t va0 = *(const typename V8S<AT>::t*)(A + ar0);
    typename V8S<AT>::t va1 = *(const typename V8S<AT>::t*)(A + ar1);
    float8 vw0 = *(const float8*)(W + wr0);
    float8 vw1 = *(const float8*)(W + wr1);

    for (int k0 = 0; k0 < K; k0 += 32) {
        __syncthreads();
        *(short8*)(As + c0 * 8) = to_bf8(va0);
        *(short8*)(As + c1 * 8) = to_bf8(va1);
        *(short8*)(Ws + c0 * 8) = to_bf8(vw0);
        *(short8*)(Ws + c1 * 8) = to_bf8(vw1);
        __syncthreads();
        int kn = k0 + 32;
        if (kn < K) {
            va0 = *(const typename V8S<AT>::t*)(A + ar0 + kn);
            va1 = *(const typename V8S<AT>::t*)(A + ar1 + kn);
            vw0 = *(const float8*)(W + wr0 + kn);
            vw1 = *(const float8*)(W + wr1 + kn);
        }
        short8 af[4], wf[4];
        #pragma unroll
        for (int i = 0; i < 4; i++)
            af[i] = *(const short8*)(As + (wm * 64 + i * 16 + l15) * 32 + quad * 8);
        #pragma unroll
        for (int j = 0; j < 4; j++)
            wf[j] = *(const short8*)(Ws + (wn * 64 + j * 16 + l15) * 32 + quad * 8);
        #pragma unroll
        for (int i = 0; i < 4; i++)
            #pragma unroll
            for (int j = 0; j < 4; j++)
                acc[i][j] = __builtin_amdgcn_mfma_f32_16x16x32_bf16(af[i], wf[j], acc[i][j], 0, 0, 0);
    }

    #pragma unroll
    for (int i = 0; i < 4; i++) {
        #pragma unroll
        for (int j = 0; j < 4; j++) {
            int nn = (int)n0 + wn * 64 + j * 16 + l15;
            #pragma unroll
            for (int v = 0; v < 4; v++) {
                long mm = m0 + wm * 64 + i * 16 + quad * 4 + v;
                float val = acc[i][j][v];
                if (MODE == 1) {
                    ((float*)Cv)[mm * N + nn] = sigmoidf_(val + bias[nn]);
                } else {
                    ((u16*)Cv)[mm * N + nn] = f2bf(clampf_(val, -1e4f, 1e4f));
                }
            }
        }
    }
}

// ---------------------------------------------------------------------------
// persistent GRU layer recurrence (cooperative launch).
// grid = 128 blocks: blockIdx = g*16 + rb; g = batch group (16 batches),
// rb = column block (64 Whg rows). Wave holds 16 Whg rows in registers.
// FENCE-FREE inter-block exchange: h state crosses blocks ONLY through
// relaxed agent-scope atomics (cache-bypassing, coherent at MALL).
// This revision vs the 6248us baseline (ONLY provably-local changes):
//   - Whz/Whr weights in 32 VGPRs/lane (wzr*/wrr*), bhg[jj] in 1 VGPR;
//     removes the wzL/wrL/bgL LDS arrays entirely.
//   - z/r h-loads vectorized: 2x ds_read_b128 per batch instead of 16
//     scalar u16 reads + 32 scalar f32 weight reads (24x fewer LDS ops).
//   - MFMA accumulator split into 2 independent chains (ae/ao).
// Sync protocol, publish path, xg loads, store placement: UNCHANGED.
__global__ __launch_bounds__(256, 1)
void recur(u16* __restrict__ xgh, const float* __restrict__ xz,
           const float* __restrict__ xr,
           const float* __restrict__ Whz, const float* __restrict__ Whr,
           const float* __restrict__ bhz, const u16* __restrict__ WhgBF,
           const float* __restrict__ bhg,
           u32* __restrict__ exA, u32* __restrict__ exB,
           float* __restrict__ hT, u32* __restrict__ cnt, u32 cbase)
{
    __shared__ alignas(16) u16   hL[16 * 1040];     // h tile (u16 cols, stride 1040)
    __shared__ alignas(16) u16   hXs[16 * 64];      // this block's new-h slice
    __shared__ alignas(16) float zF[16], rF[16];

    const int tid  = threadIdx.x;
    const int lane = tid & 63;
    const int wv   = tid >> 6;
    const int l15  = lane & 15;
    const int quad = lane >> 4;
    const int g    = blockIdx.x >> 4;         // batch group 0..7
    const int rb   = blockIdx.x & 15;         // column block 0..15
    const int m0   = g * 16;
    const int nw   = rb * 64 + wv * 16;       // wave's Whg row base

    const float bhzf = bhz[0];

    // z/r weights in registers: lane covers k = lane*8..+8 and 512+lane*8..+8
    float wzr0[8], wzr1[8], wrr0[8], wrr1[8];
    #pragma unroll
    for (int j = 0; j < 8; j++) {
        wzr0[j] = Whz[lane * 8 + j];
        wzr1[j] = Whz[512 + lane * 8 + j];
        wrr0[j] = Whr[lane * 8 + j];
        wrr1[j] = Whr[512 + lane * 8 + j];
    }

    // Whg fragments -> registers, reused 256 steps
    short8 bfr[32];
    #pragma unroll
    for (int kt = 0; kt < 32; kt++)
        bfr[kt] = *(const short8*)(WhgBF + (long)(nw + l15) * H_ + kt * 32 + quad * 8);

    const int jj = nw + l15;                  // lane's output column
    const int lj = wv * 16 + l15;             // column local to block
    const float bgj = bhg[jj];                // g-gate bias in a register
    u32* const ex0 = exA + g * 8192;
    u32* const ex1 = exB + g * 8192;
    u32* const cpt = cnt + g * 64;            // 256B-padded per-group counter
    __syncthreads();

    for (int t = 0; t < S_; t++) {
        u32* src = (t & 1) ? ex1 : ex0;
        u32* dst = (t & 1) ? ex0 : ex1;

        // stage h (16 x 1024 bf16 = 32 KB) from MALL -> LDS, u64 bypass loads
        {
            u64* s64 = (u64*)src;
            #pragma unroll
            for (int k = 0; k < 16; k++) {
                u64 v = __hip_atomic_load(s64 + k * 256 + tid,
                                          __ATOMIC_RELAXED, __HIP_MEMORY_SCOPE_AGENT);
                *(u64*)(hL + k * 1040 + tid * 4) = v;
            }
        }
        __syncthreads();

        // z/r: each wave handles 4 batches; b128 h loads, register weights
        #pragma unroll
        for (int bb = 0; bb < 4; bb++) {
            int b = wv * 4 + bb;
            const u16* hb = hL + b * 1040;
            short8 hv0 = *(const short8*)(hb + lane * 8);
            short8 hv1 = *(const short8*)(hb + 512 + lane * 8);
            float sz = 0.f, sr = 0.f;
            #pragma unroll
            for (int j = 0; j < 8; j++) {
                float f0 = bf2f((u16)hv0[j]);
                float f1 = bf2f((u16)hv1[j]);
                sz = fmaf(f0, wzr0[j], sz);
                sz = fmaf(f1, wzr1[j], sz);
                sr = fmaf(f0, wrr0[j], sr);
                sr = fmaf(f1, wrr1[j], sr);
            }
            #pragma unroll
            for (int o = 1; o < 64; o <<= 1) { sz += __shfl_xor(sz, o); sr += __shfl_xor(sr, o); }
            if (lane == 0) {
                long mrow = (long)(m0 + b) * S_ + t;
                zF[b] = sigmoidf_(sz + xz[mrow] + bhzf);
                rF[b] = sigmoidf_(sr + xr[mrow]);
            }
        }
        __syncthreads();

        // h @ Whg^T for this wave's 16 output columns: 32 MFMAs, 2 acc chains
        f32x4 ae = {0.f, 0.f, 0.f, 0.f};
        f32x4 ao = {0.f, 0.f, 0.f, 0.f};
        #pragma unroll
        for (int kt = 0; kt < 32; kt += 2) {
            short8 a0 = *(const short8*)(hL + l15 * 1040 + kt * 32 + quad * 8);
            short8 a1 = *(const short8*)(hL + l15 * 1040 + (kt + 1) * 32 + quad * 8);
            ae = __builtin_amdgcn_mfma_f32_16x16x32_bf16(a0, bfr[kt],     ae, 0, 0, 0);
            ao = __builtin_amdgcn_mfma_f32_16x16x32_bf16(a1, bfr[kt + 1], ao, 0, 0, 0);
        }
        f32x4 acc;
        #pragma unroll
        for (int v = 0; v < 4; v++) acc[v] = ae[v] + ao[v];

        // gate + update; new h slice -> LDS; hs/hT plain stores
        #pragma unroll
        for (int v = 0; v < 4; v++) {
            int  b    = quad * 4 + v;
            long row  = (long)(m0 + b) * S_ + t;
            float accv = clampf_(acc[v], -1e4f, 1e4f);
            float gpre = bf2f(xgh[row * H_ + jj]) + rF[b] * accv + bgj;
            float gv   = tanhf_(gpre);
            float hold = clampf_(bf2f(hL[b * 1040 + jj]), -4.f, 4.f);
            float z    = zF[b];
            float hnew = clampf_(z * hold + (1.f - z) * gv, -4.f, 4.f);
            u16 hb = f2bf(hnew);
            hXs[b * 64 + lj]   = hb;
            xgh[row * H_ + jj] = hb;            // in-place: xg slice -> hs slice
            if (t == S_ - 1) hT[(m0 + b) * (2 * H_) + jj] = hnew;
        }
        __syncthreads();

        // publish slice: 512 u32 per block (16 b x 32 col-pairs), bypass stores
        #pragma unroll
        for (int k = 0; k < 2; k++) {
            int i  = tid + k * 256;
            int b  = i >> 5;
            int cp = i & 31;
            u32 val = *(const u32*)(hXs + b * 64 + cp * 2);
            __hip_atomic_store(dst + b * 512 + rb * 32 + cp, val,
                               __ATOMIC_RELAXED, __HIP_MEMORY_SCOPE_AGENT);
        }
        __syncthreads();   // drains all waves' vmcnt before barrier

        // group arrival counter + spin (relaxed, MALL-resident)
        if (tid == 0) {
            __hip_atomic_fetch_add(cpt, 1u, __ATOMIC_RELAXED, __HIP_MEMORY_SCOPE_AGENT);
            u32 target = cbase + 16u * (u32)(t + 1);
            int guard = 0;
            while (__hip_atomic_load(cpt, __ATOMIC_RELAXED, __HIP_MEMORY_SCOPE_AGENT) < target
                   && guard < 20000000) {
                __builtin_amdgcn_s_sleep(2);
                guard++;
            }
        }
        __syncthreads();
    }
}

// ---------------------------------------------------------------------------
extern "C" void kernel_launch(void* const* d_in, const int* in_sizes, int n_in,
                              void* d_out, int out_size, void* d_ws, size_t ws_size,
                              hipStream_t stream)
{
    (void)in_sizes; (void)n_in; (void)out_size;
    const float* x    = (const float*)d_in[0];
    const float* h0   = (const float*)d_in[1];
    const float* Wxz0 = (const float*)d_in[2];
    const float* Whz0 = (const float*)d_in[3];
    const float* bhz0 = (const float*)d_in[4];
    const float* Wxr0 = (const float*)d_in[5];
    const float* bxr0 = (const float*)d_in[6];
    const float* Whr0 = (const float*)d_in[7];
    const float* Wxg0 = (const float*)d_in[8];
    const float* Whg0 = (const float*)d_in[9];
    const float* bhg0 = (const float*)d_in[10];
    const float* Wxz1 = (const float*)d_in[11];
    const float* Whz1 = (const float*)d_in[12];
    const float* bhz1 = (const float*)d_in[13];
    const float* Wxr1 = (const float*)d_in[14];
    const float* bxr1 = (const float*)d_in[15];
    const float* Whr1 = (const float*)d_in[16];
    const float* Wxg1 = (const float*)d_in[17];
    const float* Whg1 = (const float*)d_in[18];
    const float* bhg1 = (const float*)d_in[19];
    const float* Why  = (const float*)d_in[20];
    const float* bhy  = (const float*)d_in[21];
    float* out = (float*)d_out;

    char* ws = (char*)d_ws;
    u16*   BUF_A = (u16*)(ws);                        // xg0 -> hs0 in place (64 MB)
    u16*   BUF_B = (u16*)(ws + 67108864);             // Whg0bf | xg1 -> hs1 (64 MB)
    float* XZ    = (float*)(ws + 134217728);          // 128 KB
    float* XR    = (float*)(ws + 134348800);          // 128 KB
    u32*   EX0A  = (u32*)(ws + 134479872);            // 256 KB exchange buffers
    u32*   EX0B  = (u32*)(ws + 134742016);
    u32*   EX1A  = (u32*)(ws + 135004160);
    u32*   EX1B  = (u32*)(ws + 135266304);
    u32*   CNT   = (u32*)(ws + 135528448);            // 8 groups x 256 B
    if (ws_size < (size_t)135530496) return;

    hipMemsetAsync(CNT, 0, 2048, stream);
    init_h<<<256, 256, 0, stream>>>(h0, EX0A, EX1A);

    const int M = B_ * S_;   // 32768

    // ---- layer 0 ----
    cvt_bf<<<(H_ * H_) / 256, 256, 0, stream>>>(Whg0, BUF_B, H_ * H_);  // park in BUF_B head
    proj_zr<float><<<M / 4, 256, 0, stream>>>(x, Wxz0, Wxr0, bxr0, XZ, XR, I_);
    gemm_bt<0, float><<<dim3(H_ / 128, M / 128), 256, 0, stream>>>(x, Wxg0, nullptr, BUF_A, M, H_, I_);
    {
        u16* xgh_ = BUF_A;
        const float* xz_ = XZ; const float* xr_ = XR;
        const float* Whz_ = Whz0; const float* Whr_ = Whr0; const float* bhz_ = bhz0;
        const u16* Whg_ = BUF_B; const float* bhg_ = bhg0;
        u32* exA_ = EX0A; u32* exB_ = EX0B;
        float* hT_ = out + (long)BSO;
        u32* cnt_ = CNT; u32 cbase_ = 0;
        void* args[] = {&xgh_, &xz_, &xr_, &Whz_, &Whr_, &bhz_, &Whg_, &bhg_,
                        &exA_, &exB_, &hT_, &cnt_, &cbase_};
        hipLaunchCooperativeKernel((void*)recur, dim3(128), dim3(256), args, 0, stream);
    }

    // ---- layer 1 ----
    proj_zr<u16><<<M / 4, 256, 0, stream>>>(BUF_A, Wxz1, Wxr1, bxr1, XZ, XR, H_);
    gemm_bt<0, u16><<<dim3(H_ / 128, M / 128), 256, 0, stream>>>(BUF_A, Wxg1, nullptr, BUF_B, M, H_, H_);
    cvt_bf<<<(H_ * H_) / 256, 256, 0, stream>>>(Whg1, BUF_A, H_ * H_);  // hs0 dead now
    {
        u16* xgh_ = BUF_B;
        const float* xz_ = XZ; const float* xr_ = XR;
        const float* Whz_ = Whz1; const float* Whr_ = Whr1; const float* bhz_ = bhz1;
        const u16* Whg_ = BUF_A; const float* bhg_ = bhg1;
        u32* exA_ = EX1A; u32* exB_ = EX1B;
        float* hT_ = out + (long)BSO + H_;
        u32* cnt_ = CNT; u32 cbase_ = 16u * S_;       // counters continue monotonically
        void* args[] = {&xgh_, &xz_, &xr_, &Whz_, &Whr_, &bhz_, &Whg_, &bhg_,
                        &exA_, &exB_, &hT_, &cnt_, &cbase_};
        hipLaunchCooperativeKernel((void*)recur, dim3(128), dim3(256), args, 0, stream);
    }

    // ---- output head: sigmoid(hs1 @ Why^T + bhy) -> (B,S,O) fp32 ----
    gemm_bt<1, u16><<<dim3(O_ / 128, M / 128), 256, 0, stream>>>(BUF_B, Why, bhy, (void*)out, M, O_, H_);
}

// Round 5
// 3517.402 us; speedup vs baseline: 1.7765x; 1.4775x over previous
//
#include <hip/hip_runtime.h>
#include <stdint.h>

#define B_   128
#define S_   256
#define I_   256
#define H_   1024
#define O_   256
#define BSO  (B_*S_*O_)

typedef unsigned short u16;
typedef unsigned int   u32;
typedef unsigned long long u64;

using short8 = __attribute__((ext_vector_type(8))) short;   // 8 bf16 in 4 VGPRs
using float8 = __attribute__((ext_vector_type(8))) float;   // 8 fp32 in 8 VGPRs
using f32x4  = __attribute__((ext_vector_type(4))) float;

__device__ __forceinline__ float bf2f(u16 u) {
    return __uint_as_float(((u32)u) << 16);
}
__device__ __forceinline__ u16 f2bf(float f) {
    u32 x = __float_as_uint(f);
    x += 0x7FFFu + ((x >> 16) & 1u);   // RNE
    return (u16)(x >> 16);
}
__device__ __forceinline__ float clampf_(float x, float lo, float hi) {
    x = (x < hi) ? x : hi;
    x = (x > lo) ? x : lo;
    return x;
}
__device__ __forceinline__ float sigmoidf_(float x) {
    x = clampf_(x, -60.f, 60.f);
    return 1.0f / (1.0f + __expf(-x));
}
__device__ __forceinline__ float tanhf_(float x) {
    float x2 = clampf_(2.0f * x, -30.0f, 30.0f);
    float e = __expf(x2);
    return (e - 1.0f) / (e + 1.0f);
}

__device__ __forceinline__ float loadf(const float* p) { return *p; }
__device__ __forceinline__ float loadf(const u16* p)   { return bf2f(*p); }

template<typename T> struct V8S;
template<> struct V8S<u16>   { using t = short8; };
template<> struct V8S<float> { using t = float8; };

__device__ __forceinline__ short8 to_bf8(short8 v) { return v; }
__device__ __forceinline__ short8 to_bf8(float8 v) {
    short8 r;
    #pragma unroll
    for (int j = 0; j < 8; j++) r[j] = (short)f2bf(v[j]);
    return r;
}

// ---------------------------------------------------------------------------
// init: pack h0 (B,L,H) fp32 into per-layer exchange buffers (u32 = 2 bf16).
// ex layout per layer: [group g (16)][batch-in-group bl (8)][512 u32 (1024 cols)]
__global__ void init_h(const float* __restrict__ h0, u32* __restrict__ ex0, u32* __restrict__ ex1)
{
    int idx = blockIdx.x * 256 + threadIdx.x;   // over 128*512
    int bg = idx >> 9;          // global batch
    int cp = idx & 511;         // u32 column pair
    int g  = bg >> 3, bl = bg & 7;
    u32 lo0 = f2bf(h0[bg * 2048 + 2 * cp]);
    u32 hi0 = f2bf(h0[bg * 2048 + 2 * cp + 1]);
    ex0[g * 4096 + bl * 512 + cp] = lo0 | (hi0 << 16);
    u32 lo1 = f2bf(h0[bg * 2048 + 1024 + 2 * cp]);
    u32 hi1 = f2bf(h0[bg * 2048 + 1024 + 2 * cp + 1]);
    ex1[g * 4096 + bl * 512 + cp] = lo1 | (hi1 << 16);
}

// fp32 -> bf16 bulk convert
__global__ void cvt_bf(const float* __restrict__ in, u16* __restrict__ out, int n)
{
    int i = blockIdx.x * 256 + threadIdx.x;
    if (i < n) out[i] = f2bf(in[i]);
}

// ---------------------------------------------------------------------------
// scalar-gate projections: xz[m] = X[m,:]·Wz ; xr[m] = X[m,:]·Wr + br
template<typename XT>
__global__ __launch_bounds__(256, 4)
void proj_zr(const XT* __restrict__ X, const float* __restrict__ Wz,
             const float* __restrict__ Wr, const float* __restrict__ br,
             float* __restrict__ xz, float* __restrict__ xr, int K)
{
    const int lane = threadIdx.x & 63;
    const int wv   = threadIdx.x >> 6;
    const long m   = (long)blockIdx.x * 4 + wv;
    const XT* xp   = X + m * K;
    float az = 0.f, ar = 0.f;
    for (int i = lane; i < K; i += 64) {
        float xv = loadf(xp + i);
        az = fmaf(xv, Wz[i], az);
        ar = fmaf(xv, Wr[i], ar);
    }
    #pragma unroll
    for (int o = 1; o < 64; o <<= 1) { az += __shfl_xor(az, o); ar += __shfl_xor(ar, o); }
    if (lane == 0) {
        xz[m] = clampf_(az, -1e4f, 1e4f);
        xr[m] = clampf_(ar + br[0], -1e4f, 1e4f);
    }
}

// ---------------------------------------------------------------------------
// C[M,N] = A[M,K] · W[N,K]^T.  A: fp32 or bf16; W fp32 (both -> bf16 at LDS).
// MODE 0: store bf16. MODE 1: store fp32 sigmoid(val + bias[n]).
template<int MODE, typename AT>
__global__ __launch_bounds__(256, 2)
void gemm_bt(const AT* __restrict__ A, const float* __restrict__ W,
             const float* __restrict__ bias, void* __restrict__ Cv,
             int M, int N, int K)
{
    __shared__ alignas(16) u16 As[128 * 32];
    __shared__ alignas(16) u16 Ws[128 * 32];
    const int tid  = threadIdx.x;
    const int lane = tid & 63;
    const int wv   = tid >> 6;
    const int l15  = lane & 15;
    const int quad = lane >> 4;
    const int wm   = wv >> 1, wn = wv & 1;
    const long m0  = (long)blockIdx.y * 128;
    const long n0  = (long)blockIdx.x * 128;

    const int c0 = tid, c1 = tid + 256;
    const long ar0 = (m0 + (c0 >> 2)) * (long)K + (c0 & 3) * 8;
    const long ar1 = (m0 + (c1 >> 2)) * (long)K + (c1 & 3) * 8;
    const long wr0 = (n0 + (c0 >> 2)) * (long)K + (c0 & 3) * 8;
    const long wr1 = (n0 + (c1 >> 2)) * (long)K + (c1 & 3) * 8;

    f32x4 zero4 = {0.f, 0.f, 0.f, 0.f};
    f32x4 acc[4][4];
    #pragma unroll
    for (int i = 0; i < 4; i++)
        #pragma unroll
        for (int j = 0; j < 4; j++) acc[i][j] = zero4;

    typename V8S<AT>::t va0 = *(const typename V8S<AT>::t*)(A + ar0);
    typename V8S<AT>::t va1 = *(const typename V8S<AT>::t*)(A + ar1);
    float8 vw0 = *(const float8*)(W + wr0);
    float8 vw1 = *(const float8*)(W + wr1);

    for (int k0 = 0; k0 < K; k0 += 32) {
        __syncthreads();
        *(short8*)(As + c0 * 8) = to_bf8(va0);
        *(short8*)(As + c1 * 8) = to_bf8(va1);
        *(short8*)(Ws + c0 * 8) = to_bf8(vw0);
        *(short8*)(Ws + c1 * 8) = to_bf8(vw1);
        __syncthreads();
        int kn = k0 + 32;
        if (kn < K) {
            va0 = *(const typename V8S<AT>::t*)(A + ar0 + kn);
            va1 = *(const typename V8S<AT>::t*)(A + ar1 + kn);
            vw0 = *(const float8*)(W + wr0 + kn);
            vw1 = *(const float8*)(W + wr1 + kn);
        }
        short8 af[4], wf[4];
        #pragma unroll
        for (int i = 0; i < 4; i++)
            af[i] = *(const short8*)(As + (wm * 64 + i * 16 + l15) * 32 + quad * 8);
        #pragma unroll
        for (int j = 0; j < 4; j++)
            wf[j] = *(const short8*)(Ws + (wn * 64 + j * 16 + l15) * 32 + quad * 8);
        #pragma unroll
        for (int i = 0; i < 4; i++)
            #pragma unroll
            for (int j = 0; j < 4; j++)
                acc[i][j] = __builtin_amdgcn_mfma_f32_16x16x32_bf16(af[i], wf[j], acc[i][j], 0, 0, 0);
    }

    #pragma unroll
    for (int i = 0; i < 4; i++) {
        #pragma unroll
        for (int j = 0; j < 4; j++) {
            int nn = (int)n0 + wn * 64 + j * 16 + l15;
            #pragma unroll
            for (int v = 0; v < 4; v++) {
                long mm = m0 + wm * 64 + i * 16 + quad * 4 + v;
                float val = acc[i][j][v];
                if (MODE == 1) {
                    ((float*)Cv)[mm * N + nn] = sigmoidf_(val + bias[nn]);
                } else {
                    ((u16*)Cv)[mm * N + nn] = f2bf(clampf_(val, -1e4f, 1e4f));
                }
            }
        }
    }
}

// ---------------------------------------------------------------------------
// persistent GRU layer recurrence (cooperative launch).
// R5 revision vs the 5197us R2 baseline: SAME phase order, SAME sync shape,
// but 16 groups x 8 batches (grid 256) instead of 8 groups x 16 batches
// (grid 128). Halves per-block stage / z/r / gate / publish work and uses
// all 256 CUs. Still 16 arrivals per group per step (16 column blocks),
// same two-buffer ping-pong, same counter formula.
//   blockIdx = g*16 + rb; g = batch group (8 batches), rb = column block
//   (64 Whg rows). hL rows 8..15 are zeroed once pre-loop so the 16x16
//   MFMA A-tile is valid (D rows 8..15 = 0, unused); gate/store loops are
//   guarded b < 8.
// FENCE-FREE inter-block exchange: h state crosses blocks ONLY through
// relaxed agent-scope atomics (cache-bypassing, coherent at MALL).
__global__ __launch_bounds__(256, 1)
void recur(u16* __restrict__ xgh, const float* __restrict__ xz,
           const float* __restrict__ xr,
           const float* __restrict__ Whz, const float* __restrict__ Whr,
           const float* __restrict__ bhz, const u16* __restrict__ WhgBF,
           const float* __restrict__ bhg,
           u32* __restrict__ exA, u32* __restrict__ exB,
           float* __restrict__ hT, u32* __restrict__ cnt, u32 cbase)
{
    __shared__ alignas(16) u16   hL[16 * 1040];     // h tile (rows 8..15 zero)
    __shared__ alignas(16) u16   hXs[8 * 64];       // this block's new-h slice
    __shared__ alignas(16) float zF[8], rF[8];

    const int tid  = threadIdx.x;
    const int lane = tid & 63;
    const int wv   = tid >> 6;
    const int l15  = lane & 15;
    const int quad = lane >> 4;
    const int g    = blockIdx.x >> 4;         // batch group 0..15
    const int rb   = blockIdx.x & 15;         // column block 0..15
    const int m0   = g * 8;
    const int nw   = rb * 64 + wv * 16;       // wave's Whg row base

    const float bhzf = bhz[0];

    // z/r weights in registers: lane covers k = lane*8..+8 and 512+lane*8..+8
    float wzr0[8], wzr1[8], wrr0[8], wrr1[8];
    #pragma unroll
    for (int j = 0; j < 8; j++) {
        wzr0[j] = Whz[lane * 8 + j];
        wzr1[j] = Whz[512 + lane * 8 + j];
        wrr0[j] = Whr[lane * 8 + j];
        wrr1[j] = Whr[512 + lane * 8 + j];
    }

    // Whg fragments -> registers, reused 256 steps
    short8 bfr[32];
    #pragma unroll
    for (int kt = 0; kt < 32; kt++)
        bfr[kt] = *(const short8*)(WhgBF + (long)(nw + l15) * H_ + kt * 32 + quad * 8);

    const int jj = nw + l15;                  // lane's output column
    const int lj = wv * 16 + l15;             // column local to block
    const float bgj = bhg[jj];                // g-gate bias in a register
    u32* const ex0 = exA + g * 4096;
    u32* const ex1 = exB + g * 4096;
    u32* const cpt = cnt + g * 64;            // 256B-padded per-group counter

    // zero hL rows 8..15 once (stage never writes them; MFMA reads them)
    for (int i = tid; i < 8 * 1040; i += 256) hL[8 * 1040 + i] = 0;
    __syncthreads();

    for (int t = 0; t < S_; t++) {
        u32* src = (t & 1) ? ex1 : ex0;
        u32* dst = (t & 1) ? ex0 : ex1;

        // stage h (8 x 1024 bf16 = 16 KB) from MALL -> LDS, u64 bypass loads
        {
            u64* s64 = (u64*)src;
            #pragma unroll
            for (int k = 0; k < 8; k++) {
                u64 v = __hip_atomic_load(s64 + k * 256 + tid,
                                          __ATOMIC_RELAXED, __HIP_MEMORY_SCOPE_AGENT);
                *(u64*)(hL + k * 1040 + tid * 4) = v;
            }
        }
        __syncthreads();

        // z/r: each wave handles 2 batches; b128 h loads, register weights
        #pragma unroll
        for (int bb = 0; bb < 2; bb++) {
            int b = wv * 2 + bb;
            const u16* hb = hL + b * 1040;
            short8 hv0 = *(const short8*)(hb + lane * 8);
            short8 hv1 = *(const short8*)(hb + 512 + lane * 8);
            float sz = 0.f, sr = 0.f;
            #pragma unroll
            for (int j = 0; j < 8; j++) {
                float f0 = bf2f((u16)hv0[j]);
                float f1 = bf2f((u16)hv1[j]);
                sz = fmaf(f0, wzr0[j], sz);
                sz = fmaf(f1, wzr1[j], sz);
                sr = fmaf(f0, wrr0[j], sr);
                sr = fmaf(f1, wrr1[j], sr);
            }
            #pragma unroll
            for (int o = 1; o < 64; o <<= 1) { sz += __shfl_xor(sz, o); sr += __shfl_xor(sr, o); }
            if (lane == 0) {
                long mrow = (long)(m0 + b) * S_ + t;
                zF[b] = sigmoidf_(sz + xz[mrow] + bhzf);
                rF[b] = sigmoidf_(sr + xr[mrow]);
            }
        }
        __syncthreads();

        // h @ Whg^T for this wave's 16 output columns: 32 MFMAs, 2 acc chains
        f32x4 ae = {0.f, 0.f, 0.f, 0.f};
        f32x4 ao = {0.f, 0.f, 0.f, 0.f};
        #pragma unroll
        for (int kt = 0; kt < 32; kt += 2) {
            short8 a0 = *(const short8*)(hL + l15 * 1040 + kt * 32 + quad * 8);
            short8 a1 = *(const short8*)(hL + l15 * 1040 + (kt + 1) * 32 + quad * 8);
            ae = __builtin_amdgcn_mfma_f32_16x16x32_bf16(a0, bfr[kt],     ae, 0, 0, 0);
            ao = __builtin_amdgcn_mfma_f32_16x16x32_bf16(a1, bfr[kt + 1], ao, 0, 0, 0);
        }
        f32x4 acc;
        #pragma unroll
        for (int v = 0; v < 4; v++) acc[v] = ae[v] + ao[v];

        // gate + update for batches b = quad*4+v < 8 (quads 0,1); new h slice
        // -> LDS; hs/hT plain stores
        #pragma unroll
        for (int v = 0; v < 4; v++) {
            int b = quad * 4 + v;
            if (b < 8) {
                long row  = (long)(m0 + b) * S_ + t;
                float accv = clampf_(acc[v], -1e4f, 1e4f);
                float gpre = bf2f(xgh[row * H_ + jj]) + rF[b] * accv + bgj;
                float gv   = tanhf_(gpre);
                float hold = clampf_(bf2f(hL[b * 1040 + jj]), -4.f, 4.f);
                float z    = zF[b];
                float hnew = clampf_(z * hold + (1.f - z) * gv, -4.f, 4.f);
                u16 hb = f2bf(hnew);
                hXs[b * 64 + lj]   = hb;
                xgh[row * H_ + jj] = hb;            // in-place: xg slice -> hs slice
                if (t == S_ - 1) hT[(m0 + b) * (2 * H_) + jj] = hnew;
            }
        }
        __syncthreads();

        // publish slice: 256 u32 per block (8 b x 32 col-pairs), bypass stores
        {
            int b  = tid >> 5;
            int cp = tid & 31;
            u32 val = *(const u32*)(hXs + b * 64 + cp * 2);
            __hip_atomic_store(dst + b * 512 + rb * 32 + cp, val,
                               __ATOMIC_RELAXED, __HIP_MEMORY_SCOPE_AGENT);
        }
        __syncthreads();   // drains all waves' vmcnt before barrier

        // group arrival counter + spin (relaxed, MALL-resident)
        if (tid == 0) {
            __hip_atomic_fetch_add(cpt, 1u, __ATOMIC_RELAXED, __HIP_MEMORY_SCOPE_AGENT);
            u32 target = cbase + 16u * (u32)(t + 1);
            int guard = 0;
            while (__hip_atomic_load(cpt, __ATOMIC_RELAXED, __HIP_MEMORY_SCOPE_AGENT) < target
                   && guard < 20000000) {
                __builtin_amdgcn_s_sleep(2);
                guard++;
            }
        }
        __syncthreads();
    }
}

// ---------------------------------------------------------------------------
extern "C" void kernel_launch(void* const* d_in, const int* in_sizes, int n_in,
                              void* d_out, int out_size, void* d_ws, size_t ws_size,
                              hipStream_t stream)
{
    (void)in_sizes; (void)n_in; (void)out_size;
    const float* x    = (const float*)d_in[0];
    const float* h0   = (const float*)d_in[1];
    const float* Wxz0 = (const float*)d_in[2];
    const float* Whz0 = (const float*)d_in[3];
    const float* bhz0 = (const float*)d_in[4];
    const float* Wxr0 = (const float*)d_in[5];
    const float* bxr0 = (const float*)d_in[6];
    const float* Whr0 = (const float*)d_in[7];
    const float* Wxg0 = (const float*)d_in[8];
    const float* Whg0 = (const float*)d_in[9];
    const float* bhg0 = (const float*)d_in[10];
    const float* Wxz1 = (const float*)d_in[11];
    const float* Whz1 = (const float*)d_in[12];
    const float* bhz1 = (const float*)d_in[13];
    const float* Wxr1 = (const float*)d_in[14];
    const float* bxr1 = (const float*)d_in[15];
    const float* Whr1 = (const float*)d_in[16];
    const float* Wxg1 = (const float*)d_in[17];
    const float* Whg1 = (const float*)d_in[18];
    const float* bhg1 = (const float*)d_in[19];
    const float* Why  = (const float*)d_in[20];
    const float* bhy  = (const float*)d_in[21];
    float* out = (float*)d_out;

    char* ws = (char*)d_ws;
    u16*   BUF_A = (u16*)(ws);                        // xg0 -> hs0 in place (64 MB)
    u16*   BUF_B = (u16*)(ws + 67108864);             // Whg0bf | xg1 -> hs1 (64 MB)
    float* XZ    = (float*)(ws + 134217728);          // 128 KB
    float* XR    = (float*)(ws + 134348800);          // 128 KB
    u32*   EX0A  = (u32*)(ws + 134479872);            // 256 KB exchange buffers
    u32*   EX0B  = (u32*)(ws + 134742016);
    u32*   EX1A  = (u32*)(ws + 135004160);
    u32*   EX1B  = (u32*)(ws + 135266304);
    u32*   CNT   = (u32*)(ws + 135528448);            // 16 groups x 256 B
    if (ws_size < (size_t)135532544) return;

    hipMemsetAsync(CNT, 0, 4096, stream);
    init_h<<<256, 256, 0, stream>>>(h0, EX0A, EX1A);

    const int M = B_ * S_;   // 32768

    // ---- layer 0 ----
    cvt_bf<<<(H_ * H_) / 256, 256, 0, stream>>>(Whg0, BUF_B, H_ * H_);  // park in BUF_B head
    proj_zr<float><<<M / 4, 256, 0, stream>>>(x, Wxz0, Wxr0, bxr0, XZ, XR, I_);
    gemm_bt<0, float><<<dim3(H_ / 128, M / 128), 256, 0, stream>>>(x, Wxg0, nullptr, BUF_A, M, H_, I_);
    {
        u16* xgh_ = BUF_A;
        const float* xz_ = XZ; const float* xr_ = XR;
        const float* Whz_ = Whz0; const float* Whr_ = Whr0; const float* bhz_ = bhz0;
        const u16* Whg_ = BUF_B; const float* bhg_ = bhg0;
        u32* exA_ = EX0A; u32* exB_ = EX0B;
        float* hT_ = out + (long)BSO;
        u32* cnt_ = CNT; u32 cbase_ = 0;
        void* args[] = {&xgh_, &xz_, &xr_, &Whz_, &Whr_, &bhz_, &Whg_, &bhg_,
                        &exA_, &exB_, &hT_, &cnt_, &cbase_};
        hipLaunchCooperativeKernel((void*)recur, dim3(256), dim3(256), args, 0, stream);
    }

    // ---- layer 1 ----
    proj_zr<u16><<<M / 4, 256, 0, stream>>>(BUF_A, Wxz1, Wxr1, bxr1, XZ, XR, H_);
    gemm_bt<0, u16><<<dim3(H_ / 128, M / 128), 256, 0, stream>>>(BUF_A, Wxg1, nullptr, BUF_B, M, H_, H_);
    cvt_bf<<<(H_ * H_) / 256, 256, 0, stream>>>(Whg1, BUF_A, H_ * H_);  // hs0 dead now
    {
        u16* xgh_ = BUF_B;
        const float* xz_ = XZ; const float* xr_ = XR;
        const float* Whz_ = Whz1; const float* Whr_ = Whr1; const float* bhz_ = bhz1;
        const u16* Whg_ = BUF_A; const float* bhg_ = bhg1;
        u32* exA_ = EX1A; u32* exB_ = EX1B;
        float* hT_ = out + (long)BSO + H_;
        u32* cnt_ = CNT; u32 cbase_ = 16u * S_;       // counters continue monotonically
        void* args[] = {&xgh_, &xz_, &xr_, &Whz_, &Whr_, &bhz_, &Whg_, &bhg_,
                        &exA_, &exB_, &hT_, &cnt_, &cbase_};
        hipLaunchCooperativeKernel((void*)recur, dim3(256), dim3(256), args, 0, stream);
    }

    // ---- output head: sigmoid(hs1 @ Why^T + bhy) -> (B,S,O) fp32 ----
    gemm_bt<1, u16><<<dim3(O_ / 128, M / 128), 256, 0, stream>>>(BUF_B, Why, bhy, (void*)out, M, O_, H_);
}